// Round 10
// baseline (151.996 us; speedup 1.0000x reference)
//
#include <hip/hip_runtime.h>
#include <stdint.h>
#include <math.h>

#define N_NODES 50000
#define N_EDGES 1500000
#define HDIM 128
#define TDIM 100
#define KPAD 512         // 484 padded to multiple of 32
#define BM 64            // nodes per gru block
#define NT 512           // 8 waves = 2 mh x 4 nq
#define NBLOCKS ((N_NODES + BM - 1) / BM)   // 782

typedef __attribute__((ext_vector_type(8))) short short8v;
typedef __attribute__((ext_vector_type(4))) float f32x4;
typedef __attribute__((ext_vector_type(4))) unsigned int u32x4;

__device__ __forceinline__ unsigned short f2bf(float x) {
    unsigned int u = __float_as_uint(x);
    return (unsigned short)((u + 0x7fffu + ((u >> 16) & 1u)) >> 16);
}
__device__ __forceinline__ float sigmoidf_(float x) { return 1.0f / (1.0f + __expf(-x)); }
__device__ __forceinline__ float tanhf_(float x) { return 2.0f / (1.0f + __expf(-2.0f * x)) - 1.0f; }

__global__ void scan_edges_kernel(const int* __restrict__ dst,
                                  const float* __restrict__ edge_ts,
                                  unsigned long long* __restrict__ keys) {
    int e = blockIdx.x * 256 + threadIdx.x;
    if (e < N_EDGES) {
        unsigned tsb = __float_as_uint(__builtin_nontemporal_load(&edge_ts[e]));
        int d = __builtin_nontemporal_load(&dst[e]);
        // hi-word filter: hi is monotone non-decreasing; 32b load can't tear.
        // tsb < hi => full key strictly loses => safe skip. Ties still atomic.
        unsigned cur_hi = ((const unsigned*)keys)[2 * d + 1];
        if (tsb >= cur_hi) {
            unsigned long long key =
                ((unsigned long long)tsb << 32) | (unsigned int)(e + 1);
            atomicMax(&keys[d], key);
        }
    }
}

// Frag-major W: wbF1[bIdx][kt][lane][8], bIdx=(g3*4+nq)*2+nf, kt 0..15 (W_ih, K-pad 512)
//              wbF2[bIdx][kt][lane][8], kt 0..3 (W_hh, K=128)
__global__ void convert_w_kernel(const float* __restrict__ Wih, const float* __restrict__ Whh,
                                 unsigned short* __restrict__ wbF1, unsigned short* __restrict__ wbF2) {
    int t = blockIdx.x * 256 + threadIdx.x;
    if (t < 24576) {
        int b = t >> 10, kt = (t >> 6) & 15, l = t & 63;
        int g3 = b >> 3, nq = (b >> 1) & 3, nf = b & 1;
        int srow = g3 * 128 + nq * 32 + nf * 16 + (l & 15);
        int scol = kt * 32 + (l >> 4) * 8;
        unsigned short v[8];
        #pragma unroll
        for (int j = 0; j < 8; ++j)
            v[j] = (scol + j < 484) ? f2bf(Wih[srow * 484 + scol + j]) : (unsigned short)0;
        uint4 pk;
        pk.x = (unsigned)v[0] | ((unsigned)v[1] << 16);
        pk.y = (unsigned)v[2] | ((unsigned)v[3] << 16);
        pk.z = (unsigned)v[4] | ((unsigned)v[5] << 16);
        pk.w = (unsigned)v[6] | ((unsigned)v[7] << 16);
        *(uint4*)&wbF1[(size_t)t * 8] = pk;
    } else if (t < 24576 + 6144) {
        int t2 = t - 24576;
        int b = t2 >> 8, kt = (t2 >> 6) & 3, l = t2 & 63;
        int g3 = b >> 3, nq = (b >> 1) & 3, nf = b & 1;
        int srow = g3 * 128 + nq * 32 + nf * 16 + (l & 15);
        int scol = kt * 32 + (l >> 4) * 8;
        unsigned short v[8];
        #pragma unroll
        for (int j = 0; j < 8; ++j) v[j] = f2bf(Whh[srow * 128 + scol + j]);
        uint4 pk;
        pk.x = (unsigned)v[0] | ((unsigned)v[1] << 16);
        pk.y = (unsigned)v[2] | ((unsigned)v[3] << 16);
        pk.z = (unsigned)v[4] | ((unsigned)v[5] << 16);
        pk.w = (unsigned)v[6] | ((unsigned)v[7] << 16);
        *(uint4*)&wbF2[(size_t)t2 * 8] = pk;
    }
}

__global__ __launch_bounds__(NT, 4)
void gru_mfma_kernel(const int* __restrict__ src,
                     const float* __restrict__ edge_ts,
                     const float* __restrict__ ef,
                     const float* __restrict__ mem,
                     const float* __restrict__ lut,
                     const float* __restrict__ tw,
                     const float* __restrict__ tb,
                     const float* __restrict__ bih,
                     const float* __restrict__ bhh,
                     const unsigned short* __restrict__ wbF1,
                     const unsigned short* __restrict__ wbF2,
                     const unsigned long long* __restrict__ keys,
                     float* __restrict__ out) {
    __shared__ unsigned short Alds[BM * KPAD];   // 64 KB -> 2 blocks/CU
    const int tid = threadIdx.x;
    const int base = blockIdx.x * BM;

    // ---- staging: 8 threads per node; gather loads nontemporal ----
    {
        const int i = tid >> 3, l8 = tid & 7;
        const int n = base + i;
        if (n < N_NODES) {
            unsigned long long key = keys[n];
            const int has = (key != 0ULL);
            const int e = has ? (int)((unsigned)key - 1u) : 0;
            const int s = src[e];
            const float tv = edge_ts[e];
            const float d = tv - lut[s];
            if (l8 == 0)
                __builtin_nontemporal_store(has ? tv : lut[n],
                                            &out[(size_t)N_NODES * HDIM + n]);
            const int swg = i & 7;
            unsigned short* Arow = &Alds[i * KPAD];
            #pragma unroll
            for (int p = 0; p < 8; ++p) {
                const int gk = p * 8 + l8, k0 = gk * 8;   // 16B group 0..63
                float f[8];
                if (k0 < 384) {
                    const float* sp = (k0 < 128) ? mem + (size_t)s * HDIM + k0
                                    : (k0 < 256) ? mem + (size_t)n * HDIM + (k0 - 128)
                                                 : ef + (size_t)e * HDIM + (k0 - 256);
                    u32x4 w0 = __builtin_nontemporal_load((const u32x4*)sp);
                    u32x4 w1 = __builtin_nontemporal_load((const u32x4*)sp + 1);
                    f[0]=__uint_as_float(w0.x); f[1]=__uint_as_float(w0.y);
                    f[2]=__uint_as_float(w0.z); f[3]=__uint_as_float(w0.w);
                    f[4]=__uint_as_float(w1.x); f[5]=__uint_as_float(w1.y);
                    f[6]=__uint_as_float(w1.z); f[7]=__uint_as_float(w1.w);
                } else {
                    #pragma unroll
                    for (int j2 = 0; j2 < 8; ++j2) {
                        int q = k0 - 384 + j2;
                        f[j2] = (q < TDIM) ? cosf(fmaf(d, tw[q], tb[q])) : 0.f;
                    }
                }
                uint4 pk;
                pk.x = (unsigned)f2bf(f[0]) | ((unsigned)f2bf(f[1]) << 16);
                pk.y = (unsigned)f2bf(f[2]) | ((unsigned)f2bf(f[3]) << 16);
                pk.z = (unsigned)f2bf(f[4]) | ((unsigned)f2bf(f[5]) << 16);
                pk.w = (unsigned)f2bf(f[6]) | ((unsigned)f2bf(f[7]) << 16);
                *(uint4*)&Arow[(size_t)(gk ^ swg) * 8] = pk;
            }
        }
    }
    __syncthreads();

    // ---- MFMA GEMMs: 8 waves = 2 M-halves x 4 N-quarters ----
    const int w = tid >> 6, l = tid & 63;
    const int mh = w >> 2, nq = w & 3;
    const int lr = l & 15, lh = l >> 4;

    const short8v* Bv1 = (const short8v*)wbF1 + l;
    const short8v* Bv2 = (const short8v*)wbF2 + l;
    int bo1[6], bo2[6];
    #pragma unroll
    for (int f = 0; f < 6; ++f) {
        const int bidx = ((f >> 1) * 4 + nq) * 2 + (f & 1);
        bo1[f] = bidx * 16 * 64;
        bo2[f] = bidx * 4 * 64;
    }

    const f32x4 fzero = {0.f, 0.f, 0.f, 0.f};
    f32x4 acc[4][2][2];  // q=0 r(i+h), q=1 z(i+h), q=2 i_n, q=3 h_n
    #pragma unroll
    for (int q = 0; q < 4; ++q)
        #pragma unroll
        for (int nf = 0; nf < 2; ++nf)
            #pragma unroll
            for (int mf = 0; mf < 2; ++mf) acc[q][nf][mf] = fzero;

    // GEMM1: gi = A(K=512) @ W_ih^T. ALL 6 B-loads issued before any MFMA
    // consumes them -> 6-deep MLP per wave (the round-6..9 kernels serialized
    // each load at full latency: load -> waitcnt -> mfma).
    #pragma unroll 2
    for (int kt = 0; kt < 16; ++kt) {
        short8v b[6];
        #pragma unroll
        for (int f = 0; f < 6; ++f) b[f] = Bv1[bo1[f] + kt * 64];
        short8v a[2];
        #pragma unroll
        for (int mf = 0; mf < 2; ++mf) {
            const int row = mh * 32 + mf * 16 + lr;
            a[mf] = *(const short8v*)&Alds[row * KPAD + ((kt * 32 + lh * 8) ^ ((row & 7) << 3))];
        }
        #pragma unroll
        for (int f = 0; f < 6; ++f)
            #pragma unroll
            for (int mf = 0; mf < 2; ++mf)
                acc[f >> 1][f & 1][mf] = __builtin_amdgcn_mfma_f32_16x16x32_bf16(
                    a[mf], b[f], acc[f >> 1][f & 1][mf], 0, 0, 0);
    }
    // GEMM2: gh = mem_s @ W_hh^T (A k-slice 128..256), same hoisted-batch shape.
    #pragma unroll 2
    for (int kt = 0; kt < 4; ++kt) {
        short8v b[6];
        #pragma unroll
        for (int f = 0; f < 6; ++f) b[f] = Bv2[bo2[f] + kt * 64];
        short8v a[2];
        #pragma unroll
        for (int mf = 0; mf < 2; ++mf) {
            const int row = mh * 32 + mf * 16 + lr;
            a[mf] = *(const short8v*)&Alds[row * KPAD + (((128 + kt * 32) + lh * 8) ^ ((row & 7) << 3))];
        }
        #pragma unroll
        for (int f = 0; f < 6; ++f) {
            const int q = (f >> 1) < 2 ? (f >> 1) : 3;
            #pragma unroll
            for (int mf = 0; mf < 2; ++mf)
                acc[q][f & 1][mf] = __builtin_amdgcn_mfma_f32_16x16x32_bf16(
                    a[mf], b[f], acc[q][f & 1][mf], 0, 0, 0);
        }
    }

    // ---- GRU epilogue (nt: don't evict weights from L2) ----
    float br[2], bz[2], bin[2], bhn[2];
    #pragma unroll
    for (int nf = 0; nf < 2; ++nf) {
        const int c = nq * 32 + nf * 16 + lr;
        br[nf] = bih[c] + bhh[c];
        bz[nf] = bih[HDIM + c] + bhh[HDIM + c];
        bin[nf] = bih[2 * HDIM + c];
        bhn[nf] = bhh[2 * HDIM + c];
    }
    #pragma unroll
    for (int mf = 0; mf < 2; ++mf)
        #pragma unroll
        for (int ii = 0; ii < 4; ++ii) {
            const int row = mh * 32 + mf * 16 + lh * 4 + ii;
            const int node = base + row;
            if (node >= N_NODES) continue;
            const bool has = keys[node] != 0ULL;
            #pragma unroll
            for (int nf = 0; nf < 2; ++nf) {
                const int c = nq * 32 + nf * 16 + lr;
                const float r = sigmoidf_(acc[0][nf][mf][ii] + br[nf]);
                const float z = sigmoidf_(acc[1][nf][mf][ii] + bz[nf]);
                const float ng = tanhf_(acc[2][nf][mf][ii] + bin[nf] +
                                        r * (acc[3][nf][mf][ii] + bhn[nf]));
                const float h = __builtin_nontemporal_load(&mem[(size_t)node * HDIM + c]);
                __builtin_nontemporal_store(has ? (1.f - z) * ng + z * h : h,
                                            &out[(size_t)node * HDIM + c]);
            }
        }
}

extern "C" void kernel_launch(void* const* d_in, const int* in_sizes, int n_in,
                              void* d_out, int out_size, void* d_ws, size_t ws_size,
                              hipStream_t stream) {
    const int* src       = (const int*)d_in[0];
    const int* dst       = (const int*)d_in[1];
    const float* edge_ts = (const float*)d_in[2];
    const float* ef      = (const float*)d_in[3];
    const float* mem     = (const float*)d_in[4];
    const float* lut     = (const float*)d_in[5];
    const float* tw      = (const float*)d_in[6];
    const float* tb      = (const float*)d_in[7];
    const float* Wih     = (const float*)d_in[8];
    const float* Whh     = (const float*)d_in[9];
    const float* bih     = (const float*)d_in[10];
    const float* bhh     = (const float*)d_in[11];
    float* out = (float*)d_out;

    char* ws = (char*)d_ws;
    unsigned long long* keys = (unsigned long long*)ws;      // 400000 B (region 512K)
    unsigned short* wbF1 = (unsigned short*)(ws + 524288);   // 393216 B
    unsigned short* wbF2 = (unsigned short*)(ws + 917504);   //  98304 B

    hipMemsetAsync(keys, 0, (size_t)N_NODES * 8, stream);
    scan_edges_kernel<<<(N_EDGES + 255) / 256, 256, 0, stream>>>(dst, edge_ts, keys);
    convert_w_kernel<<<(24576 + 6144 + 255) / 256, 256, 0, stream>>>(Wih, Whh, wbF1, wbF2);
    gru_mfma_kernel<<<NBLOCKS, NT, 0, stream>>>(
        src, edge_ts, ef, mem, lut, tw, tb, bih, bhh, wbF1, wbF2, keys, out);
}